// Round 1
// baseline (157.807 us; speedup 1.0000x reference)
//
#include <hip/hip_runtime.h>
#include <stdint.h>
#include <stddef.h>

// Problem constants (match reference).
#define Bn 32
#define Tn 512
#define Vn 64
#define Fn 64
#define TT 32   // timesteps per workgroup chunk -> grid = 32 * 16 = 512 blocks

typedef __attribute__((ext_vector_type(8))) short bfx8;  // 8 bf16 (4 VGPRs)
typedef __attribute__((ext_vector_type(4))) float fx4;   // MFMA accumulator

// fp32 -> bf16, round-to-nearest-even (inputs are finite; no NaN handling needed)
__device__ __forceinline__ short f2bf(float f) {
    union { float f; uint32_t u; } c; c.f = f;
    uint32_t u = c.u;
    return (short)((u + 0x7FFFu + ((u >> 16) & 1u)) >> 16);
}

// LDS: W-tile (setup only) unioned with Theta fragments (run phase).
union SetupRun {
    float wt[64][65];          // padded W[b] tile
    short tf[32][64][8];       // Theta frags: [gt*8+k*2+fh][lane][e], 32 KB
};

__global__ __launch_bounds__(256, 2) void gcjk_main(
    const float* __restrict__ x, const float* __restrict__ W,
    const float* __restrict__ Theta, float* __restrict__ out)
{
    __shared__ __align__(16) SetupRun sr;
    __shared__ float degs[64];
    __shared__ __align__(16) short xt[2][64][72]; // Xt[f][u] bf16, padded (stride 144B = 9*16)

    const int tid  = threadIdx.x;
    const int lane = tid & 63;
    const int wv   = tid >> 6;     // wave id 0..3 -> owns v-block 16*wv
    const int l15  = lane & 15;
    const int gg   = lane >> 4;    // lane group 0..3

    const int bid = blockIdx.x;
    const int b   = bid >> 4;          // 16 chunks per b
    const int t0  = (bid & 15) * TT;

    // ---- setup: load W[b] into LDS (coalesced float4) ----
    const float* Wb = W + b * (Vn * Vn);
    {
        const float4* W4 = (const float4*)Wb;
        #pragma unroll
        for (int c = 0; c < 4; ++c) {
            float4 wvv = W4[c * 256 + tid];
            int flat = (c * 256 + tid) * 4;
            int i = flat >> 6, j = flat & 63;
            sr.wt[i][j+0] = wvv.x; sr.wt[i][j+1] = wvv.y;
            sr.wt[i][j+2] = wvv.z; sr.wt[i][j+3] = wvv.w;
        }
    }
    __syncthreads();
    // deg[j] = sum_i W[b,i,j]  (column sum, applied later on the ROW index, per reference)
    if (tid < 64) {
        float s = 0.f;
        for (int i = 0; i < 64; ++i) s += sr.wt[i][tid];
        degs[tid] = s;
    }
    __syncthreads();

    // ---- A fragments (stage-1 B-operand), registers, reused for all t ----
    // af[k][s] element e = T_k[u = 32s+8gg+e][v = 16wv+l15]
    bfx8 af[4][2];
    #pragma unroll
    for (int s = 0; s < 2; ++s) {
        #pragma unroll
        for (int e = 0; e < 8; ++e) {
            int u = 32*s + 8*gg + e;
            int v = 16*wv + l15;
            float wuv = sr.wt[u][v];
            float lt  = ((u == v) ? (degs[u] - 1.0f) : 0.0f) - wuv;  // (D - W - I)
            float p0  = (u == v) ? 1.0f : 0.0f;
            float p1  = lt;
            float p2  = 2.0f*lt*p1 - p0;   // elementwise Chebyshev recurrence
            float p3  = 2.0f*lt*p2 - p1;
            af[0][s][e] = f2bf(p0);
            af[1][s][e] = f2bf(p1);
            af[2][s][e] = f2bf(p2);
            af[3][s][e] = f2bf(p3);
        }
    }
    __syncthreads();   // done reading sr.wt; union space becomes tf

    // ---- Theta fragments (stage-2 A-operand) into LDS, exact per-lane read order ----
    // frag = gt*8 + k*2 + fh; element e: Theta[k][f][g],
    //   f = 16*(2*fh + (e>>2)) + 4*gg + (e&3),  g = 16*gt + l15
    #pragma unroll
    for (int fi = 0; fi < 8; ++fi) {
        int frag = wv * 8 + fi;
        int gt = frag >> 3, k = (frag >> 1) & 3, fh = frag & 1;
        int g  = 16*gt + l15;
        #pragma unroll
        for (int e = 0; e < 8; ++e) {
            int f = 16*(2*fh + (e>>2)) + 4*gg + (e&3);
            sr.tf[frag][lane][e] = f2bf(Theta[(k*Fn + f)*Fn + g]);
        }
    }

    // ---- initial stage of t0 into xt[0]: Xt[f][u] = bf16(x[b,t0,u,f]) ----
    {
        const float4* xs4 = (const float4*)(x + (size_t)(b * Tn + t0) * (Vn * Fn));
        #pragma unroll
        for (int c = 0; c < 4; ++c) {
            int chunk = c * 256 + tid;
            float4 xv = xs4[chunk];
            int u = chunk >> 4, f0 = (chunk & 15) * 4;
            xt[0][f0+0][u] = f2bf(xv.x);
            xt[0][f0+1][u] = f2bf(xv.y);
            xt[0][f0+2][u] = f2bf(xv.z);
            xt[0][f0+3][u] = f2bf(xv.w);
        }
    }
    __syncthreads();

    // ---- main t loop, double-buffered Xt with issue-early / write-late staging ----
    for (int ts = 0; ts < TT; ++ts) {
        const int t   = t0 + ts;
        const int cur = ts & 1;
        const float* xb = x + (size_t)(b * Tn + t) * (Vn * Fn);

        // issue next tile's global loads early (latency hides under MFMA below)
        float4 pre[4];
        if (ts + 1 < TT) {
            const float4* nx4 = (const float4*)(x + (size_t)(b * Tn + t + 1) * (Vn * Fn));
            #pragma unroll
            for (int c = 0; c < 4; ++c) pre[c] = nx4[c * 256 + tid];
        }

        // X fragments (stage-1 A-operand): Xt rows f = 16ft+l15, cols u = 32s+8gg..+7
        bfx8 xf[4][2];
        #pragma unroll
        for (int ft = 0; ft < 4; ++ft) {
            #pragma unroll
            for (int s = 0; s < 2; ++s)
                xf[ft][s] = *(const bfx8*)&xt[cur][16*ft + l15][32*s + 8*gg];
        }

        fx4 oacc[4] = {fx4{0,0,0,0}, fx4{0,0,0,0}, fx4{0,0,0,0}, fx4{0,0,0,0}};
        #pragma unroll
        for (int k = 0; k < 4; ++k) {
            // stage 1: PT_k[f][v] = sum_u Xt[f][u] * T_k[u][v]   (tiles ft x (vt=wv))
            fx4 pacc[4] = {fx4{0,0,0,0}, fx4{0,0,0,0}, fx4{0,0,0,0}, fx4{0,0,0,0}};
            #pragma unroll
            for (int ft = 0; ft < 4; ++ft) {
                pacc[ft] = __builtin_amdgcn_mfma_f32_16x16x32_bf16(xf[ft][0], af[k][0], pacc[ft], 0, 0, 0);
                pacc[ft] = __builtin_amdgcn_mfma_f32_16x16x32_bf16(xf[ft][1], af[k][1], pacc[ft], 0, 0, 0);
            }
            // stage 2: out'[g][v] += Theta'[g][kf] * PT[kf][v]
            // C-layout of pacc lands exactly in the B-operand lane positions: pure register repack.
            #pragma unroll
            for (int fh = 0; fh < 2; ++fh) {
                fx4 pa = pacc[2*fh], pb = pacc[2*fh+1];
                bfx8 pf;
                pf[0]=f2bf(pa[0]); pf[1]=f2bf(pa[1]); pf[2]=f2bf(pa[2]); pf[3]=f2bf(pa[3]);
                pf[4]=f2bf(pb[0]); pf[5]=f2bf(pb[1]); pf[6]=f2bf(pb[2]); pf[7]=f2bf(pb[3]);
                #pragma unroll
                for (int gt = 0; gt < 4; ++gt) {
                    bfx8 th = *(const bfx8*)&sr.tf[gt*8 + k*2 + fh][lane][0];
                    oacc[gt] = __builtin_amdgcn_mfma_f32_16x16x32_bf16(th, pf, oacc[gt], 0, 0, 0);
                }
            }
        }

        // epilogue: relu(out) + sigmoid(x), packed float4 stores
        {
            const int v = 16*wv + l15;
            float* ob = out + (size_t)(b * Tn + t) * (Vn * Fn);
            #pragma unroll
            for (int gt = 0; gt < 4; ++gt) {
                int g0 = 16*gt + 4*gg;   // C rows: g = 16gt + 4gg + r
                float4 xv = *(const float4*)(xb + v * Fn + g0);  // L1-hot re-read
                fx4 o = oacc[gt];
                float4 r;
                r.x = fmaxf(o[0], 0.f) + __fdividef(1.f, 1.f + __expf(-xv.x));
                r.y = fmaxf(o[1], 0.f) + __fdividef(1.f, 1.f + __expf(-xv.y));
                r.z = fmaxf(o[2], 0.f) + __fdividef(1.f, 1.f + __expf(-xv.z));
                r.w = fmaxf(o[3], 0.f) + __fdividef(1.f, 1.f + __expf(-xv.w));
                *(float4*)(ob + v * Fn + g0) = r;
            }
        }

        // write-late: commit the prefetched next tile into the other buffer
        if (ts + 1 < TT) {
            #pragma unroll
            for (int c = 0; c < 4; ++c) {
                int chunk = c * 256 + tid;
                int u = chunk >> 4, f0 = (chunk & 15) * 4;
                float4 xv = pre[c];
                xt[cur^1][f0+0][u] = f2bf(xv.x);
                xt[cur^1][f0+1][u] = f2bf(xv.y);
                xt[cur^1][f0+2][u] = f2bf(xv.z);
                xt[cur^1][f0+3][u] = f2bf(xv.w);
            }
        }
        __syncthreads();
    }
}

extern "C" void kernel_launch(void* const* d_in, const int* in_sizes, int n_in,
                              void* d_out, int out_size, void* d_ws, size_t ws_size,
                              hipStream_t stream) {
    (void)in_sizes; (void)n_in; (void)out_size; (void)d_ws; (void)ws_size;
    const float* x  = (const float*)d_in[0];
    const float* W  = (const float*)d_in[1];
    const float* Th = (const float*)d_in[2];
    float* o = (float*)d_out;
    gcjk_main<<<dim3(Bn * (Tn / TT)), dim3(256), 0, stream>>>(x, W, Th, o);
}